// Round 1
// baseline (406.374 us; speedup 1.0000x reference)
//
#include <hip/hip_runtime.h>
#include <stdint.h>

#define NBATCH 2
#define LL 4096
#define CC 256

typedef short bf16x8 __attribute__((ext_vector_type(8)));
typedef float f32x4 __attribute__((ext_vector_type(4)));

__device__ __forceinline__ uint16_t f2bf(float f){
  union { float f; uint32_t u; } v; v.f = f;
  return (uint16_t)((v.u + 0x7fffu + ((v.u >> 16) & 1u)) >> 16);
}

__device__ __forceinline__ void md_merge(float& m, float& d, float om, float od){
  float nm = fmaxf(m, om);
  d = d * expf(m - nm) + od * expf(om - nm);
  m = nm;
}

// ---------------- cast fp32 -> bf16 ----------------
__global__ __launch_bounds__(256) void cast_bf16(
    const float* __restrict__ a, const float* __restrict__ b,
    uint16_t* __restrict__ oa, uint16_t* __restrict__ ob){
  int idx = blockIdx.x * 256 + threadIdx.x;   // over float4 groups, grid is exact
  float4 va = ((const float4*)a)[idx];
  float4 vb = ((const float4*)b)[idx];
  ushort4 ua, ub;
  ua.x = f2bf(va.x); ua.y = f2bf(va.y); ua.z = f2bf(va.z); ua.w = f2bf(va.w);
  ub.x = f2bf(vb.x); ub.y = f2bf(vb.y); ub.z = f2bf(vb.z); ub.w = f2bf(vb.w);
  ((ushort4*)oa)[idx] = ua;
  ((ushort4*)ob)[idx] = ub;
}

// ---------------- 64x64 conf tile via MFMA (gemm_bt pattern) ----------------
// conf[l,s] = dot(F0[l,:], F1[s,:]) / 16
// wave wv covers l-rows [wv*16, wv*16+16); 4 accs over s subtiles.
// C/D layout: s-offset = lane&15, l-offset = (lane>>4)*4 + reg  [verified m89]
__device__ __forceinline__ void conf_tile(
    const uint16_t* __restrict__ A, const uint16_t* __restrict__ B,
    int lt, int st, int wv, int lane, float cv[4][4]){
  const int lr = lane & 15, quad = lane >> 4;
  f32x4 acc0 = {0.f,0.f,0.f,0.f}, acc1 = acc0, acc2 = acc0, acc3 = acc0;
  const uint16_t* arow = A + (size_t)(lt*64 + wv*16 + lr) * CC + quad*8;
  const uint16_t* brow = B + (size_t)(st*64 + lr) * CC + quad*8;
  #pragma unroll
  for (int k = 0; k < CC; k += 32){
    bf16x8 af = *(const bf16x8*)(arow + k);
    bf16x8 b0 = *(const bf16x8*)(brow + k);
    bf16x8 b1 = *(const bf16x8*)(brow + 16*CC + k);
    bf16x8 b2 = *(const bf16x8*)(brow + 32*CC + k);
    bf16x8 b3 = *(const bf16x8*)(brow + 48*CC + k);
    acc0 = __builtin_amdgcn_mfma_f32_16x16x32_bf16(af, b0, acc0, 0, 0, 0);
    acc1 = __builtin_amdgcn_mfma_f32_16x16x32_bf16(af, b1, acc1, 0, 0, 0);
    acc2 = __builtin_amdgcn_mfma_f32_16x16x32_bf16(af, b2, acc2, 0, 0, 0);
    acc3 = __builtin_amdgcn_mfma_f32_16x16x32_bf16(af, b3, acc3, 0, 0, 0);
  }
  #pragma unroll
  for (int r = 0; r < 4; r++){
    cv[0][r] = acc0[r] * 0.0625f;
    cv[1][r] = acc1[r] * 0.0625f;
    cv[2][r] = acc2[r] * 0.0625f;
    cv[3][r] = acc3[r] * 0.0625f;
  }
}

// ---------------- pass 1: per-row / per-col (max, sumexp) partials ----------------
__global__ __launch_bounds__(256) void conf_pass1(
    const uint16_t* __restrict__ f0b, const uint16_t* __restrict__ f1b,
    float2* __restrict__ rowpart, float2* __restrict__ colpart){
  int st = blockIdx.x, lt = blockIdx.y, n = blockIdx.z;
  int tid = threadIdx.x, wv = tid >> 6, lane = tid & 63;
  int lr = lane & 15, quad = lane >> 4;
  const uint16_t* A = f0b + (size_t)n * LL * CC;
  const uint16_t* B = f1b + (size_t)n * LL * CC;
  float cv[4][4];
  conf_tile(A, B, lt, st, wv, lane, cv);

  // row stats: max/sumexp over the 64 s-columns of this tile, per l
  float pm[4], pd[4];
  #pragma unroll
  for (int r = 0; r < 4; r++){
    float m = fmaxf(fmaxf(cv[0][r], cv[1][r]), fmaxf(cv[2][r], cv[3][r]));
    float d = 0.f;
    #pragma unroll
    for (int j = 0; j < 4; j++) d += expf(cv[j][r] - m);
    pm[r] = m; pd[r] = d;
  }
  #pragma unroll
  for (int msk = 1; msk <= 8; msk <<= 1){
    #pragma unroll
    for (int r = 0; r < 4; r++){
      float mm = __shfl_xor(pm[r], msk);
      float dd = __shfl_xor(pd[r], msk);
      md_merge(pm[r], pd[r], mm, dd);
    }
  }
  if (lr == 0){
    #pragma unroll
    for (int r = 0; r < 4; r++){
      int l = lt*64 + wv*16 + quad*4 + r;
      rowpart[((size_t)n*LL + l) * 64 + st] = make_float2(pm[r], pd[r]);
    }
  }

  // col stats: max/sumexp over the 64 l-rows of this tile, per s
  float qm[4], qd[4];
  #pragma unroll
  for (int j = 0; j < 4; j++){
    float m = fmaxf(fmaxf(cv[j][0], cv[j][1]), fmaxf(cv[j][2], cv[j][3]));
    float d = 0.f;
    #pragma unroll
    for (int r = 0; r < 4; r++) d += expf(cv[j][r] - m);
    qm[j] = m; qd[j] = d;
  }
  #pragma unroll
  for (int msk = 16; msk <= 32; msk <<= 1){
    #pragma unroll
    for (int j = 0; j < 4; j++){
      float mm = __shfl_xor(qm[j], msk);
      float dd = __shfl_xor(qd[j], msk);
      md_merge(qm[j], qd[j], mm, dd);
    }
  }
  __shared__ float scm[4][64], scd[4][64];
  if (quad == 0){
    #pragma unroll
    for (int j = 0; j < 4; j++){ scm[wv][j*16+lr] = qm[j]; scd[wv][j*16+lr] = qd[j]; }
  }
  __syncthreads();
  if (tid < 64){
    float m = scm[0][tid], d = scd[0][tid];
    #pragma unroll
    for (int w = 1; w < 4; w++) md_merge(m, d, scm[w][tid], scd[w][tid]);
    colpart[((size_t)n*LL + st*64 + tid) * 64 + lt] = make_float2(m, d);
  }
}

// ---------------- reduce (max,sumexp) partials: 64 -> 1 per row ----------------
__global__ __launch_bounds__(256) void reduce_softmax(
    const float2* __restrict__ part, float* __restrict__ om, float* __restrict__ od){
  int row = blockIdx.x * 4 + (threadIdx.x >> 6);
  int lane = threadIdx.x & 63;
  float2 p = part[(size_t)row * 64 + lane];
  float m = p.x, d = p.y;
  #pragma unroll
  for (int msk = 1; msk <= 32; msk <<= 1){
    float mm = __shfl_xor(m, msk);
    float dd = __shfl_xor(d, msk);
    md_merge(m, d, mm, dd);
  }
  if (lane == 0){ om[row] = m; od[row] = d; }
}

// ---------------- pass 2: conf' argmax partials ----------------
__global__ __launch_bounds__(256) void conf_pass2(
    const uint16_t* __restrict__ f0b, const uint16_t* __restrict__ f1b,
    const float* __restrict__ rm, const float* __restrict__ rs,
    const float* __restrict__ cm, const float* __restrict__ cs,
    float2* __restrict__ rowarg, float2* __restrict__ colarg){
  int st = blockIdx.x, lt = blockIdx.y, n = blockIdx.z;
  int tid = threadIdx.x, wv = tid >> 6, lane = tid & 63;
  int lr = lane & 15, quad = lane >> 4;
  __shared__ float lrm[64], lrsi[64], lcm[64], lcsi[64];
  if (tid < 64){
    lrm[tid]  = rm[(size_t)n*LL + lt*64 + tid];
    lrsi[tid] = 1.f / rs[(size_t)n*LL + lt*64 + tid];
    lcm[tid]  = cm[(size_t)n*LL + st*64 + tid];
    lcsi[tid] = 1.f / cs[(size_t)n*LL + st*64 + tid];
  }
  const uint16_t* A = f0b + (size_t)n * LL * CC;
  const uint16_t* B = f1b + (size_t)n * LL * CC;
  float cv[4][4];
  conf_tile(A, B, lt, st, wv, lane, cv);
  __syncthreads();
  // conf'[l,s] = exp(2c - rm_l - cm_s) / (rs_l * cs_s)
  float pv[4][4];
  #pragma unroll
  for (int j = 0; j < 4; j++){
    int ss = j*16 + lr;
    #pragma unroll
    for (int r = 0; r < 4; r++){
      int ll = wv*16 + quad*4 + r;
      pv[j][r] = expf(2.f*cv[j][r] - lrm[ll] - lcm[ss]) * lrsi[ll] * lcsi[ss];
    }
  }
  // row argmax over s
  float bv[4]; int bi[4];
  #pragma unroll
  for (int r = 0; r < 4; r++){
    float v = pv[0][r]; int i = st*64 + lr;
    #pragma unroll
    for (int j = 1; j < 4; j++){
      if (pv[j][r] > v){ v = pv[j][r]; i = st*64 + j*16 + lr; }
    }
    bv[r] = v; bi[r] = i;
  }
  #pragma unroll
  for (int msk = 1; msk <= 8; msk <<= 1){
    #pragma unroll
    for (int r = 0; r < 4; r++){
      float v2 = __shfl_xor(bv[r], msk);
      int   i2 = __shfl_xor(bi[r], msk);
      if (v2 > bv[r]){ bv[r] = v2; bi[r] = i2; }
    }
  }
  if (lr == 0){
    #pragma unroll
    for (int r = 0; r < 4; r++){
      int l = lt*64 + wv*16 + quad*4 + r;
      rowarg[((size_t)n*LL + l)*64 + st] = make_float2(bv[r], __int_as_float(bi[r]));
    }
  }
  // col argmax over l
  float qv[4]; int qi[4];
  #pragma unroll
  for (int j = 0; j < 4; j++){
    float v = pv[j][0]; int i = lt*64 + wv*16 + quad*4;
    #pragma unroll
    for (int r = 1; r < 4; r++){
      if (pv[j][r] > v){ v = pv[j][r]; i = lt*64 + wv*16 + quad*4 + r; }
    }
    qv[j] = v; qi[j] = i;
  }
  #pragma unroll
  for (int msk = 16; msk <= 32; msk <<= 1){
    #pragma unroll
    for (int j = 0; j < 4; j++){
      float v2 = __shfl_xor(qv[j], msk);
      int   i2 = __shfl_xor(qi[j], msk);
      if (v2 > qv[j]){ qv[j] = v2; qi[j] = i2; }
    }
  }
  __shared__ float sav[4][64]; __shared__ int sai[4][64];
  if (quad == 0){
    #pragma unroll
    for (int j = 0; j < 4; j++){ sav[wv][j*16+lr] = qv[j]; sai[wv][j*16+lr] = qi[j]; }
  }
  __syncthreads();
  if (tid < 64){
    float v = sav[0][tid]; int i = sai[0][tid];
    #pragma unroll
    for (int w = 1; w < 4; w++){
      if (sav[w][tid] > v){ v = sav[w][tid]; i = sai[w][tid]; }
    }
    colarg[((size_t)n*LL + st*64 + tid)*64 + lt] = make_float2(v, __int_as_float(i));
  }
}

// ---------------- reduce argmax partials ----------------
__global__ __launch_bounds__(256) void reduce_arg(
    const float2* __restrict__ part, float* __restrict__ ov, int* __restrict__ oi){
  int row = blockIdx.x * 4 + (threadIdx.x >> 6);
  int lane = threadIdx.x & 63;
  float2 p = part[(size_t)row * 64 + lane];
  float v = p.x; int i = __float_as_int(p.y);
  #pragma unroll
  for (int msk = 1; msk <= 32; msk <<= 1){
    float v2 = __shfl_xor(v, msk);
    int   i2 = __shfl_xor(i, msk);
    if (v2 > v){ v = v2; i = i2; }
  }
  if (lane == 0){ ov[row] = v; oi[row] = i; }
}

// ---------------- on-the-fly fea for the rare mask hit ----------------
// fea[s,c] = sum_w u(s,w,c) * sem(s,w);  sem(s,w) = (1/256) sum_c feat[s,c]*u(s,w,c)
// u(s=(h,x), w=(dy,dx), c) = featflat[c*4096 + (h+dy-1)*64 + (x+dx-1)]  (0 pad)
__device__ float fea_fly(const float* __restrict__ featn, int srow, int t){
  __shared__ float sred[9][4];
  __shared__ float ssem[9];
  int lane = t & 63, wv = t >> 6;
  int h = srow >> 6, xx = srow & 63;
  float fv = featn[(size_t)srow * CC + t];
  float uv[9];
  #pragma unroll
  for (int w = 0; w < 9; w++){
    int dy = w/3 - 1, dx = w%3 - 1;
    int y = h + dy, x = xx + dx;
    uv[w] = (y >= 0 && y < 64 && x >= 0 && x < 64) ? featn[(size_t)t * 4096 + y*64 + x] : 0.f;
  }
  __syncthreads();
  #pragma unroll
  for (int w = 0; w < 9; w++){
    float pvv = fv * uv[w];
    #pragma unroll
    for (int msk = 1; msk <= 32; msk <<= 1) pvv += __shfl_xor(pvv, msk);
    if (lane == 0) sred[w][wv] = pvv;
  }
  __syncthreads();
  if (t < 9) ssem[t] = (sred[t][0] + sred[t][1] + sred[t][2] + sred[t][3]) * (1.f/256.f);
  __syncthreads();
  float acc = 0.f;
  #pragma unroll
  for (int w = 0; w < 9; w++) acc += uv[w] * ssem[w];
  __syncthreads();
  return acc;
}

// ---------------- pass 3: mutual-NN scatter into s0/s1 ----------------
__global__ __launch_bounds__(256) void scatter_s(
    const float* __restrict__ feat0, const float* __restrict__ feat1,
    const float* __restrict__ rowVal, const int* __restrict__ rowIdx,
    const float* __restrict__ colVal, const int* __restrict__ colIdx,
    float* __restrict__ s0, float* __restrict__ s1){
  int l = blockIdx.x, n = blockIdx.y, t = threadIdx.x;
  size_t base = (size_t)n * LL;
  {
    int ss = rowIdx[base + l];            // always valid index
    float v = 0.f;
    if (rowVal[base + l] > 0.2f && colIdx[base + ss] == l)   // block-uniform cond
      v = fea_fly(feat1 + (size_t)n*LL*CC, ss, t) * (1.f/4096.f);
    s0[(base + l) * CC + t] = v;
  }
  {
    int ss = colIdx[base + l];
    float v = 0.f;
    if (colVal[base + l] > 0.2f && rowIdx[base + ss] == l)
      v = fea_fly(feat0 + (size_t)n*LL*CC, ss, t) * (1.f/4096.f);
    s1[(base + l) * CC + t] = v;
  }
}

// ---------------- adaptive pool (over channels) + layernorm ----------------
__global__ __launch_bounds__(256) void pool_ln(
    const float* __restrict__ feat0, const float* __restrict__ feat1,
    const float* __restrict__ s0, const float* __restrict__ s1,
    const float* __restrict__ lnw, const float* __restrict__ lnb,
    float* __restrict__ out){
  int l = blockIdx.x, b = blockIdx.y, t = threadIdx.x;
  int n = b & 1;  // b in 0..3 ; 0,1 -> feat_s0/s0 ; 2,3 -> feat_s1/s1
  const float* feat = ((b < 2) ? feat0 : feat1) + ((size_t)n*LL + l) * CC;
  const float* srow = ((b < 2) ? s0 : s1) + ((size_t)n*LL + l) * CC;
  __shared__ float lf[CC], lsr[CC];
  lf[t] = feat[t];
  lsr[t] = srow[t];
  __syncthreads();
  float v;
  if (t < 160){
    int s = (t*8)/5, e = (t*8+12)/5;          // torch adaptive pool 256->160
    float sum = 0.f;
    for (int i = s; i < e; i++) sum += lf[i];
    v = sum / (float)(e - s);
  } else {
    int tt = t - 160;
    int s = (tt*8)/3, e = (tt*8+10)/3;        // 256->96
    float sum = 0.f;
    for (int i = s; i < e; i++) sum += lsr[i];
    v = sum / (float)(e - s);
  }
  float sm = v, sq = v*v;
  #pragma unroll
  for (int msk = 1; msk <= 32; msk <<= 1){
    sm += __shfl_xor(sm, msk);
    sq += __shfl_xor(sq, msk);
  }
  __shared__ float red_s[4], red_q[4];
  int lane = t & 63, wv = t >> 6;
  if (lane == 0){ red_s[wv] = sm; red_q[wv] = sq; }
  __syncthreads();
  float tot_s = red_s[0] + red_s[1] + red_s[2] + red_s[3];
  float tot_q = red_q[0] + red_q[1] + red_q[2] + red_q[3];
  float mu = tot_s * (1.f/256.f);
  float var = tot_q * (1.f/256.f) - mu*mu;
  out[((size_t)b*LL + l) * CC + t] = (v - mu) * rsqrtf(var + 1e-5f) * lnw[t] + lnb[t];
}

extern "C" void kernel_launch(void* const* d_in, const int* in_sizes, int n_in,
                              void* d_out, int out_size, void* d_ws, size_t ws_size,
                              hipStream_t stream){
  const float* feat0 = (const float*)d_in[0];
  const float* feat1 = (const float*)d_in[1];
  const float* lnw   = (const float*)d_in[2];
  const float* lnb   = (const float*)d_in[3];
  float* out = (float*)d_out;
  char* ws = (char*)d_ws;
  const size_t MB = 1024 * 1024;
  uint16_t* f0b = (uint16_t*)(ws + 0);
  uint16_t* f1b = (uint16_t*)(ws + 4*MB);
  float2* partA = (float2*)(ws + 8*MB);     // row partials / row-arg partials (reused)
  float2* partB = (float2*)(ws + 12*MB);    // col partials / col-arg partials (reused)
  float* stats  = (float*)(ws + 16*MB);
  float* rm = stats;            // [2*4096] each
  float* rs = stats + 8192;
  float* cm = stats + 16384;
  float* cs = stats + 24576;
  float* rowVal = stats + 32768;
  int*   rowIdx = (int*)(stats + 40960);
  float* colVal = stats + 49152;
  int*   colIdx = (int*)(stats + 57344);
  float* s0 = (float*)(ws + 16*MB + 262144);        // 8 MB
  float* s1 = s0 + (size_t)NBATCH*LL*CC;            // 8 MB  (total ws ~= 33.8 MB)

  cast_bf16<<<2048, 256, 0, stream>>>(feat0, feat1, f0b, f1b);
  dim3 gconf(64, 64, NBATCH);
  conf_pass1<<<gconf, 256, 0, stream>>>(f0b, f1b, partA, partB);
  reduce_softmax<<<NBATCH*LL/4, 256, 0, stream>>>(partA, rm, rs);
  reduce_softmax<<<NBATCH*LL/4, 256, 0, stream>>>(partB, cm, cs);
  conf_pass2<<<gconf, 256, 0, stream>>>(f0b, f1b, rm, rs, cm, cs, partA, partB);
  reduce_arg<<<NBATCH*LL/4, 256, 0, stream>>>(partA, rowVal, rowIdx);
  reduce_arg<<<NBATCH*LL/4, 256, 0, stream>>>(partB, colVal, colIdx);
  dim3 gsc(LL, NBATCH);
  scatter_s<<<gsc, 256, 0, stream>>>(feat0, feat1, rowVal, rowIdx, colVal, colIdx, s0, s1);
  dim3 gpl(LL, 2*NBATCH);
  pool_ln<<<gpl, 256, 0, stream>>>(feat0, feat1, s0, s1, lnw, lnb, out);
}

// Round 2
// 187.833 us; speedup vs baseline: 2.1635x; 2.1635x over previous
//
#include <hip/hip_runtime.h>
#include <stdint.h>

#define NBATCH 2
#define LL 4096
#define CC 256
#define NEG_INF -3.0e38f
#define LSTR 72   // padded LDS row stride in bf16 elements (64 + 8)

typedef short bf16x8 __attribute__((ext_vector_type(8)));
typedef float f32x4 __attribute__((ext_vector_type(4)));

__device__ __forceinline__ uint16_t f2bf(float f){
  union { float f; uint32_t u; } v; v.f = f;
  return (uint16_t)((v.u + 0x7fffu + ((v.u >> 16) & 1u)) >> 16);
}

// ---------------- cast fp32 -> bf16 ----------------
__global__ __launch_bounds__(256) void cast_bf16(
    const float* __restrict__ a, const float* __restrict__ b,
    uint16_t* __restrict__ oa, uint16_t* __restrict__ ob){
  int idx = blockIdx.x * 256 + threadIdx.x;   // float4 groups, grid exact
  float4 va = ((const float4*)a)[idx];
  float4 vb = ((const float4*)b)[idx];
  ushort4 ua, ub;
  ua.x = f2bf(va.x); ua.y = f2bf(va.y); ua.z = f2bf(va.z); ua.w = f2bf(va.w);
  ub.x = f2bf(vb.x); ub.y = f2bf(vb.y); ub.z = f2bf(vb.z); ub.w = f2bf(vb.w);
  ((ushort4*)oa)[idx] = ua;
  ((ushort4*)ob)[idx] = ub;
}

// ---------------- 128x128 LDS-staged conf tile (m93 pattern) ----------------
// acc[r][j][rr]: raw dot (no /16).  l = lq*64 + r*16 + quad*4 + rr,
//                                   s = sq*64 + j*16 + lr      [C/D layout m89]
__device__ __forceinline__ void conf_tile128(
    const uint16_t* __restrict__ A, const uint16_t* __restrict__ B,
    uint16_t* Alds, uint16_t* Blds, int lt, int st, int t, f32x4 acc[4][4]){
  const int wv = t >> 6, lane = t & 63, lr = lane & 15, quad = lane >> 4;
  const int lq = wv >> 1, sq = wv & 1;
  #pragma unroll
  for (int r = 0; r < 4; r++)
    #pragma unroll
    for (int j = 0; j < 4; j++) acc[r][j] = (f32x4){0.f,0.f,0.f,0.f};
  for (int kc = 0; kc < 4; kc++){
    __syncthreads();
    #pragma unroll
    for (int m = 0; m < 4; m++){
      int f = m*256 + t, row = f >> 3, kg = f & 7;
      *(float4*)(Alds + row*LSTR + kg*8) =
          *(const float4*)(A + (size_t)(lt*128 + row)*CC + kc*64 + kg*8);
      *(float4*)(Blds + row*LSTR + kg*8) =
          *(const float4*)(B + (size_t)(st*128 + row)*CC + kc*64 + kg*8);
    }
    __syncthreads();
    #pragma unroll
    for (int kk = 0; kk < 2; kk++){
      bf16x8 a[4], b[4];
      #pragma unroll
      for (int r = 0; r < 4; r++)
        a[r] = *(const bf16x8*)(Alds + (lq*64 + r*16 + lr)*LSTR + kk*32 + quad*8);
      #pragma unroll
      for (int j = 0; j < 4; j++)
        b[j] = *(const bf16x8*)(Blds + (sq*64 + j*16 + lr)*LSTR + kk*32 + quad*8);
      #pragma unroll
      for (int r = 0; r < 4; r++)
        #pragma unroll
        for (int j = 0; j < 4; j++)
          acc[r][j] = __builtin_amdgcn_mfma_f32_16x16x32_bf16(a[r], b[j], acc[r][j], 0, 0, 0);
    }
  }
}

// ---------------- pass 1: R_l = sum_s exp(c), C_s = sum_l exp(c) ----------------
__global__ __launch_bounds__(256) void conf_pass1(
    const uint16_t* __restrict__ f0b, const uint16_t* __restrict__ f1b,
    float* __restrict__ R, float* __restrict__ Cv){
  __shared__ uint16_t Alds[128*LSTR], Blds[128*LSTR];
  __shared__ float rowS[128], colS[128];
  int st = blockIdx.x, lt = blockIdx.y, n = blockIdx.z;
  int t = threadIdx.x;
  if (t < 128){ rowS[t] = 0.f; colS[t] = 0.f; }
  const uint16_t* A = f0b + (size_t)n*LL*CC;
  const uint16_t* B = f1b + (size_t)n*LL*CC;
  f32x4 acc[4][4];
  conf_tile128(A, B, Alds, Blds, lt, st, t, acc);
  int wv = t >> 6, lane = t & 63, lr = lane & 15, quad = lane >> 4;
  int lq = wv >> 1, sq = wv & 1;
  float rsum[4][4], csum[4] = {0.f,0.f,0.f,0.f};
  #pragma unroll
  for (int r = 0; r < 4; r++)
    #pragma unroll
    for (int rr = 0; rr < 4; rr++) rsum[r][rr] = 0.f;
  #pragma unroll
  for (int r = 0; r < 4; r++)
    #pragma unroll
    for (int j = 0; j < 4; j++)
      #pragma unroll
      for (int rr = 0; rr < 4; rr++){
        float e = expf(acc[r][j][rr] * 0.0625f);
        rsum[r][rr] += e;
        csum[j] += e;
      }
  #pragma unroll
  for (int msk = 1; msk <= 8; msk <<= 1)
    #pragma unroll
    for (int r = 0; r < 4; r++)
      #pragma unroll
      for (int rr = 0; rr < 4; rr++) rsum[r][rr] += __shfl_xor(rsum[r][rr], msk);
  #pragma unroll
  for (int msk = 16; msk <= 32; msk <<= 1)
    #pragma unroll
    for (int j = 0; j < 4; j++) csum[j] += __shfl_xor(csum[j], msk);
  if (lr == 0){
    #pragma unroll
    for (int r = 0; r < 4; r++)
      #pragma unroll
      for (int rr = 0; rr < 4; rr++)
        atomicAdd(&rowS[lq*64 + r*16 + quad*4 + rr], rsum[r][rr]);
  }
  if (quad == 0){
    #pragma unroll
    for (int j = 0; j < 4; j++) atomicAdd(&colS[sq*64 + j*16 + lr], csum[j]);
  }
  __syncthreads();
  if (t < 128){
    atomicAdd(&R [(size_t)n*LL + lt*128 + t], rowS[t]);
    atomicAdd(&Cv[(size_t)n*LL + st*128 + t], colS[t]);
  }
}

// ---------------- pass 2: log-domain argmax partials ----------------
__global__ __launch_bounds__(256) void conf_pass2(
    const uint16_t* __restrict__ f0b, const uint16_t* __restrict__ f1b,
    const float* __restrict__ R, const float* __restrict__ Cv,
    float2* __restrict__ rowPart, float2* __restrict__ colPart){
  __shared__ uint16_t Alds[128*LSTR], Blds[128*LSTR];
  __shared__ float lnR[128], lnC[128];
  __shared__ float2 rb[128][2], cb[128][2];
  int st = blockIdx.x, lt = blockIdx.y, n = blockIdx.z;
  int t = threadIdx.x;
  if (t < 128){
    lnR[t] = logf(R [(size_t)n*LL + lt*128 + t]);
    lnC[t] = logf(Cv[(size_t)n*LL + st*128 + t]);
  }
  const uint16_t* A = f0b + (size_t)n*LL*CC;
  const uint16_t* B = f1b + (size_t)n*LL*CC;
  f32x4 acc[4][4];
  conf_tile128(A, B, Alds, Blds, lt, st, t, acc);
  int wv = t >> 6, lane = t & 63, lr = lane & 15, quad = lane >> 4;
  int lq = wv >> 1, sq = wv & 1;
  const float sc = 0.125f;   // 2/16
  // row argmax over this block's 128 s (key = 2c - lnC_s)
  #pragma unroll
  for (int r = 0; r < 4; r++)
    #pragma unroll
    for (int rr = 0; rr < 4; rr++){
      float bk = NEG_INF; int bi = 0;
      #pragma unroll
      for (int j = 0; j < 4; j++){
        int sl = sq*64 + j*16 + lr;
        float key = acc[r][j][rr]*sc - lnC[sl];
        if (key > bk){ bk = key; bi = st*128 + sl; }
      }
      #pragma unroll
      for (int msk = 1; msk <= 8; msk <<= 1){
        float ok = __shfl_xor(bk, msk); int oi = __shfl_xor(bi, msk);
        if (ok > bk){ bk = ok; bi = oi; }
      }
      if (lr == 0) rb[lq*64 + r*16 + quad*4 + rr][sq] = make_float2(bk, __int_as_float(bi));
    }
  // col argmax over this block's 128 l (key = 2c - lnR_l)
  #pragma unroll
  for (int j = 0; j < 4; j++){
    float ck = NEG_INF; int ci = 0;
    #pragma unroll
    for (int r = 0; r < 4; r++)
      #pragma unroll
      for (int rr = 0; rr < 4; rr++){
        int ll = lq*64 + r*16 + quad*4 + rr;
        float key = acc[r][j][rr]*sc - lnR[ll];
        if (key > ck){ ck = key; ci = lt*128 + ll; }
      }
    #pragma unroll
    for (int msk = 16; msk <= 32; msk <<= 1){
      float ok = __shfl_xor(ck, msk); int oi = __shfl_xor(ci, msk);
      if (ok > ck){ ck = ok; ci = oi; }
    }
    if (quad == 0) cb[sq*64 + j*16 + lr][lq] = make_float2(ck, __int_as_float(ci));
  }
  __syncthreads();
  if (t < 128){
    float2 a = rb[t][0], b = rb[t][1];
    rowPart[((size_t)n*LL + lt*128 + t)*32 + st] = (a.x >= b.x) ? a : b;
    float2 c = cb[t][0], d = cb[t][1];
    colPart[((size_t)n*LL + st*128 + t)*32 + lt] = (c.x >= d.x) ? c : d;
  }
}

// ---------------- reduce argmax partials: 32 -> 1 ----------------
__global__ __launch_bounds__(256) void reduce_arg(
    const float2* __restrict__ part, float* __restrict__ okey, int* __restrict__ oidx){
  int row = blockIdx.x * 4 + (threadIdx.x >> 6);
  int lane = threadIdx.x & 63;
  float v = NEG_INF; int i = 0;
  if (lane < 32){
    float2 p = part[(size_t)row*32 + lane];
    v = p.x; i = __float_as_int(p.y);
  }
  #pragma unroll
  for (int msk = 1; msk <= 32; msk <<= 1){
    float v2 = __shfl_xor(v, msk); int i2 = __shfl_xor(i, msk);
    if (v2 > v){ v = v2; i = i2; }
  }
  if (lane == 0){ okey[row] = v; oidx[row] = i; }
}

// ---------------- on-the-fly fea for the rare mask hit ----------------
__device__ float fea_fly(const float* __restrict__ featn, int srow, int t){
  __shared__ float sred[9][4];
  __shared__ float ssem[9];
  int lane = t & 63, wv = t >> 6;
  int h = srow >> 6, xx = srow & 63;
  float fv = featn[(size_t)srow * CC + t];
  float uv[9];
  #pragma unroll
  for (int w = 0; w < 9; w++){
    int dy = w/3 - 1, dx = w%3 - 1;
    int y = h + dy, x = xx + dx;
    uv[w] = (y >= 0 && y < 64 && x >= 0 && x < 64) ? featn[(size_t)t * 4096 + y*64 + x] : 0.f;
  }
  __syncthreads();
  #pragma unroll
  for (int w = 0; w < 9; w++){
    float pvv = fv * uv[w];
    #pragma unroll
    for (int msk = 1; msk <= 32; msk <<= 1) pvv += __shfl_xor(pvv, msk);
    if (lane == 0) sred[w][wv] = pvv;
  }
  __syncthreads();
  if (t < 9) ssem[t] = (sred[t][0] + sred[t][1] + sred[t][2] + sred[t][3]) * (1.f/256.f);
  __syncthreads();
  float acc = 0.f;
  #pragma unroll
  for (int w = 0; w < 9; w++) acc += uv[w] * ssem[w];
  __syncthreads();
  return acc;
}

// ---------------- pool 256->(160|96) + LN for one output row ----------------
__device__ void pool_one(const float* __restrict__ frow, float sval,
                         const float* __restrict__ lnw, const float* __restrict__ lnb,
                         float* __restrict__ orow, int t){
  __shared__ float lf[CC], ls[CC];
  __shared__ float red_s[4], red_q[4];
  __syncthreads();
  lf[t] = frow[t];
  ls[t] = sval;
  __syncthreads();
  float v;
  if (t < 160){
    int s = (t*8)/5, e = (t*8+12)/5;
    float sum = 0.f;
    for (int i = s; i < e; i++) sum += lf[i];
    v = sum / (float)(e - s);
  } else {
    int tt = t - 160;
    int s = (tt*8)/3, e = (tt*8+10)/3;
    float sum = 0.f;
    for (int i = s; i < e; i++) sum += ls[i];
    v = sum / (float)(e - s);
  }
  float sm = v, sq = v*v;
  #pragma unroll
  for (int msk = 1; msk <= 32; msk <<= 1){
    sm += __shfl_xor(sm, msk);
    sq += __shfl_xor(sq, msk);
  }
  int lane = t & 63, wv = t >> 6;
  if (lane == 0){ red_s[wv] = sm; red_q[wv] = sq; }
  __syncthreads();
  float tot_s = red_s[0] + red_s[1] + red_s[2] + red_s[3];
  float tot_q = red_q[0] + red_q[1] + red_q[2] + red_q[3];
  float mu = tot_s * (1.f/256.f);
  float var = tot_q * (1.f/256.f) - mu*mu;
  orow[t] = (v - mu) * rsqrtf(var + 1e-5f) * lnw[t] + lnb[t];
  __syncthreads();
}

// ---------------- fused tail: mutual-NN scatter + pool + LN ----------------
__global__ __launch_bounds__(256) void tail(
    const float* __restrict__ feat0, const float* __restrict__ feat1,
    const float* __restrict__ R, const float* __restrict__ Cv,
    const float* __restrict__ rowKey, const int* __restrict__ rowIdx,
    const float* __restrict__ colKey, const int* __restrict__ colIdx,
    const float* __restrict__ lnw, const float* __restrict__ lnb,
    float* __restrict__ out){
  int l = blockIdx.x, n = blockIdx.y, t = threadIdx.x;
  size_t base = (size_t)n * LL;
  float v0 = 0.f, v1 = 0.f;
  {
    int ss = rowIdx[base + l];
    float val = expf(rowKey[base + l] - logf(R[base + l]));
    if (val > 0.2f && colIdx[base + ss] == l)
      v0 = fea_fly(feat1 + (size_t)n*LL*CC, ss, t) * (1.f/4096.f);
  }
  {
    int ss = colIdx[base + l];
    float val = expf(colKey[base + l] - logf(Cv[base + l]));
    if (val > 0.2f && rowIdx[base + ss] == l)
      v1 = fea_fly(feat0 + (size_t)n*LL*CC, ss, t) * (1.f/4096.f);
  }
  pool_one(feat0 + (base + l)*CC, v0, lnw, lnb, out + ((size_t)n*LL + l)*CC, t);
  pool_one(feat1 + (base + l)*CC, v1, lnw, lnb, out + ((size_t)(2 + n)*LL + l)*CC, t);
}

extern "C" void kernel_launch(void* const* d_in, const int* in_sizes, int n_in,
                              void* d_out, int out_size, void* d_ws, size_t ws_size,
                              hipStream_t stream){
  const float* feat0 = (const float*)d_in[0];
  const float* feat1 = (const float*)d_in[1];
  const float* lnw   = (const float*)d_in[2];
  const float* lnb   = (const float*)d_in[3];
  float* out = (float*)d_out;
  char* ws = (char*)d_ws;
  const size_t MB = 1024 * 1024;
  uint16_t* f0b = (uint16_t*)(ws + 0);
  uint16_t* f1b = (uint16_t*)(ws + 4*MB);
  float* R  = (float*)(ws + 8*MB);                 // [2*4096]
  float* Cv = (float*)(ws + 8*MB + 32*1024);       // [2*4096]
  float* rowKey = (float*)(ws + 8*MB + 64*1024);
  int*   rowIdx = (int*)  (ws + 8*MB + 96*1024);
  float* colKey = (float*)(ws + 8*MB + 128*1024);
  int*   colIdx = (int*)  (ws + 8*MB + 160*1024);
  float2* rowPart = (float2*)(ws + 9*MB);          // [8192][32] = 2 MB
  float2* colPart = (float2*)(ws + 11*MB);         // 2 MB

  cast_bf16<<<2048, 256, 0, stream>>>(feat0, feat1, f0b, f1b);
  hipMemsetAsync(R, 0, 64*1024, stream);           // zero R and Cv (contiguous)
  dim3 gconf(32, 32, NBATCH);
  conf_pass1<<<gconf, 256, 0, stream>>>(f0b, f1b, R, Cv);
  conf_pass2<<<gconf, 256, 0, stream>>>(f0b, f1b, R, Cv, rowPart, colPart);
  reduce_arg<<<NBATCH*LL/4, 256, 0, stream>>>(rowPart, rowKey, rowIdx);
  reduce_arg<<<NBATCH*LL/4, 256, 0, stream>>>(colPart, colKey, colIdx);
  dim3 gt(LL, NBATCH);
  tail<<<gt, 256, 0, stream>>>(feat0, feat1, R, Cv, rowKey, rowIdx,
                               colKey, colIdx, lnw, lnb, out);
}